// Round 7
// baseline (618.723 us; speedup 1.0000x reference)
//
#include <hip/hip_runtime.h>
#include <hip/hip_bf16.h>

typedef __attribute__((ext_vector_type(8))) short short8;
typedef __attribute__((ext_vector_type(4))) float f32x4;

#define NTOP 1000
#define KC   256
#define MROWS 40000

static __device__ __forceinline__ unsigned short f2bf(float x) {
    union { float f; unsigned u; } v; v.f = x;
    unsigned r = (v.u + 0x7FFFu + ((v.u >> 16) & 1u)) >> 16;
    return (unsigned short)r;
}

// spread bits 0..7 of x to bit positions 0,4,8,...,28
static __device__ __forceinline__ unsigned spread4(unsigned x) {
    x = (x | (x << 12)) & 0x000F000Fu;
    x = (x | (x << 6))  & 0x03030303u;
    x = (x | (x << 3))  & 0x11111111u;
    return x;
}

// Kernel 1: colsum[j] += sum over an 8-row slab of nw. colsum pre-zeroed by memset.
__global__ void k_prep(const float* __restrict__ nw,
                       float* __restrict__ colsum) {
    int j  = blockIdx.x * 256 + threadIdx.x;
    int i0 = blockIdx.y * 8;
    if (j < NTOP) {
        float s = 0.f;
        int iend = min(i0 + 8, NTOP);
        for (int i = i0; i < iend; ++i) s += nw[(size_t)i * NTOP + j];
        atomicAdd(colsum + j, s);
    }
}

// Kernel 2: build B' in MFMA-fragment order:
//   B'[((nt*8 + s)*64 + lane)] (short8) = V_j[n = nt*16 + (lane&15),
//                                             k = s*32 + (lane>>4)*8 + j]
__global__ void k_vj(const float* __restrict__ V,
                     const float* __restrict__ noise,
                     const float* __restrict__ colsum,
                     unsigned short* __restrict__ Bp) {
    int t  = blockIdx.x * 256 + threadIdx.x;   // 0 .. 32767
    int nt = t >> 9;
    int s  = (t >> 6) & 7;
    int l  = t & 63;
    int lm = l & 15, lq = l >> 4;
    int n  = nt * 16 + lm;
    int k0 = s * 32 + lq * 8;
    union { short8 v; unsigned short us[8]; } pk;
    if (n < NTOP) {
        float cs = colsum[n];
        #pragma unroll
        for (int j = 0; j < 8; ++j) {
            int idx = n * KC + k0 + j;
            pk.us[j] = f2bf(V[idx] * cs + 0.1f * noise[idx]);
        }
    } else {
        #pragma unroll
        for (int j = 0; j < 8; ++j) pk.us[j] = 0;
    }
    reinterpret_cast<short8*>(Bp)[t] = pk.v;
}

// Kernel 2b: ballot-based C compression (coalesced 1 KB reads, LDS transpose,
// coalesced writes). maskT[hs][m] bit b <=> C[m][hs*32+b] == 1 (b = col mod 32).
__global__ __launch_bounds__(256) void k_cmask(const int* __restrict__ C,
                                               unsigned int* __restrict__ maskT) {
    __shared__ unsigned int lmask[32][32];   // [hs][row-in-block] 4 KB
    const int tid  = threadIdx.x;
    const int wave = tid >> 6;
    const int l    = tid & 63;
    const int rbase = blockIdx.x * 32;

    #pragma unroll 2
    for (int rr = 0; rr < 8; ++rr) {
        const int row = wave * 8 + rr;                 // 0..31
        const int* crow = C + (size_t)(rbase + row) * NTOP;
        #pragma unroll
        for (int c = 0; c < 4; ++c) {
            const int col = c * 256 + l * 4;
            int4 v = make_int4(0, 0, 0, 0);
            if (col + 3 < NTOP) v = *reinterpret_cast<const int4*>(crow + col);
            unsigned long long b0 = __ballot(v.x == 1);
            unsigned long long b1 = __ballot(v.y == 1);
            unsigned long long b2 = __ballot(v.z == 1);
            unsigned long long b3 = __ballot(v.w == 1);
            if (l < 8) {
                unsigned w = spread4((unsigned)(b0 >> (l * 8)) & 0xffu)
                           | (spread4((unsigned)(b1 >> (l * 8)) & 0xffu) << 1)
                           | (spread4((unsigned)(b2 >> (l * 8)) & 0xffu) << 2)
                           | (spread4((unsigned)(b3 >> (l * 8)) & 0xffu) << 3);
                lmask[c * 8 + l][row] = w;
            }
        }
    }
    __syncthreads();
    const int hs = tid >> 3, ch = tid & 7;
    *reinterpret_cast<int4*>(maskT + (size_t)hs * MROWS + rbase + ch * 4) =
        *reinterpret_cast<const int4*>(&lmask[hs][ch * 4]);
}

// ---------------- k_main v8 ----------------
// 8 waves (512 thr), M_BLK=64 (wr 0..3 m-tile, wc 0..1 n-half), grid 625.
// Triple-buffered Bf LDS (3 x 16 KB = 48 KB), stage depth 2, RAW s_barrier +
// counted vmcnt asm (never 0 in loop). R/mask consumed ONE iter after issue.
// Steady-state per iter: issue R/M(hs+1) + stage(hs+2); ds_read+8 MFMA from
// buf[cur]; epilogue(hs) on last iter's R/M; vmcnt(4) retires stage(hs+1)
// (the 2 oldest VMEM ops, FIFO-safe); raw barrier; rotate.
__global__ __launch_bounds__(512, 6) void k_main(
    const float* __restrict__ U, const float* __restrict__ w5,
    const float* __restrict__ b1, const short8* __restrict__ Bf,
    const float* __restrict__ R, const unsigned int* __restrict__ maskT,
    float* __restrict__ out)
{
    __shared__ short8 BfL[3][1024];   // 3 x 16 KB triple buffer

    const int tid  = threadIdx.x;
    const int wave = tid >> 6;
    const int l    = tid & 63;
    const int lm = l & 15;
    const int lq = l >> 4;
    const int wr = wave >> 1;          // m-tile 0..3
    const int wc = wave & 1;           // n-half
    const int m  = (blockIdx.x << 6) + (wr << 4) + lm;

    // stage one 16 KB hs-tile: 512 threads x 2 x 16 B, linear LDS dest
    auto stage = [&](int buf, int hs) {
        const char* src = (const char*)Bf + ((size_t)hs << 14) + (size_t)tid * 16;
        char*       dst = (char*)&BfL[buf][0] + (size_t)tid * 16;
        __builtin_amdgcn_global_load_lds(
            (const __attribute__((address_space(1))) unsigned int*)src,
            (__attribute__((address_space(3))) unsigned int*)dst, 16, 0, 0);
        __builtin_amdgcn_global_load_lds(
            (const __attribute__((address_space(1))) unsigned int*)(src + 8192),
            (__attribute__((address_space(3))) unsigned int*)(dst + 8192), 16, 0, 0);
    };

    // prologue: stage hs=0,1 (depth 2); afr build hides the latency
    stage(0, 0);
    stage(1, 1);

    const float w0 = w5[0], w1 = w5[1], w2 = w5[2], w3 = w5[3], w4 = w5[4];
    const float bb = b1[0];
    short8 afr[8];
    #pragma unroll
    for (int s = 0; s < 8; ++s) {
        const float4* up4 = reinterpret_cast<const float4*>(
            U + (size_t)(m * KC + s * 32 + lq * 8) * 5);
        float u[40];
        #pragma unroll
        for (int i = 0; i < 10; ++i) {
            float4 t4 = up4[i];
            u[i*4+0] = t4.x; u[i*4+1] = t4.y; u[i*4+2] = t4.z; u[i*4+3] = t4.w;
        }
        union { short8 v; unsigned short us[8]; } pk;
        #pragma unroll
        for (int j = 0; j < 8; ++j) {
            const float* uu = u + j * 5;
            float e = uu[0]*w0 + uu[1]*w1 + uu[2]*w2 + uu[3]*w3 + uu[4]*w4 + bb;
            pk.us[j] = f2bf(e);
        }
        afr[s] = pk.v;
    }

    const size_t rowbase = (size_t)m * NTOP;

    // first R/mask (consumed in iter 0)
    unsigned mwc = maskT[m];
    float4 r4c = *reinterpret_cast<const float4*>(R + rowbase + wc * 16 + lq * 4);

    // buf0 staged? afr-build's compiler waits already retired stage(0,1);
    // vmcnt(4) is a safe upper bound either way.
    asm volatile("s_waitcnt vmcnt(4)" ::: "memory");
    __builtin_amdgcn_s_barrier();
    __builtin_amdgcn_sched_barrier(0);

    float lpsum = 0.f;
    int cur = 0;

    for (int hs = 0; hs < 32; ++hs) {
        // 1-ahead R/mask issue
        float4 r4n = r4c; unsigned mwn = mwc;
        if (hs < 31) {
            mwn = maskT[(size_t)(hs + 1) * MROWS + m];
            int nb = (hs + 1) * 32 + wc * 16 + lq * 4;
            nb = nb < 996 ? nb : 996;            // tail clamp; bits mask OOB
            r4n = *reinterpret_cast<const float4*>(R + rowbase + nb);
        }
        // 2-ahead stage
        if (hs < 30) {
            const int nxt2 = cur >= 1 ? cur - 1 : 2;   // (cur+2)%3
            stage(nxt2, hs + 2);
        }

        f32x4 acc = (f32x4){0.f, 0.f, 0.f, 0.f};
        #pragma unroll
        for (int s = 0; s < 8; ++s) {
            const short8 bfr = BfL[cur][((wc * 8 + s) << 6) + l];
            acc = __builtin_amdgcn_mfma_f32_16x16x32_bf16(bfr, afr[s], acc, 0, 0, 0);
        }

        // epilogue(hs): lane holds m (fixed), n = hs*32 + wc*16 + lq*4 + r
        const float* rp = reinterpret_cast<const float*>(&r4c);
        #pragma unroll
        for (int r = 0; r < 4; ++r) {
            const int bit = wc * 16 + lq * 4 + r;   // col mod 32
            float x   = acc[r];
            float muv = 1.f / (1.f + __expf(-x));
            float d   = rp[r] - muv;
            float lp  = -50.f * d * d + 1.3836465597893728f;
            if ((mwc >> bit) & 1u) lpsum += lp;
        }

        // counted wait: retire stage(hs+1) (oldest 2 in VMEM FIFO), keep
        // R/M(hs+1) + stage(hs+2) in flight. Never vmcnt(0).
        if (hs < 30) {
            asm volatile("s_waitcnt vmcnt(4)" ::: "memory");
        } else if (hs == 30) {
            asm volatile("s_waitcnt vmcnt(2)" ::: "memory");
        }
        if (hs < 31) {
            __builtin_amdgcn_s_barrier();
            __builtin_amdgcn_sched_barrier(0);
        }
        r4c = r4n; mwc = mwn;
        cur = cur < 2 ? cur + 1 : 0;
    }

    #pragma unroll
    for (int off = 32; off > 0; off >>= 1) lpsum += __shfl_down(lpsum, off);
    if (l == 0) atomicAdd(out, lpsum);
}

extern "C" void kernel_launch(void* const* d_in, const int* in_sizes, int n_in,
                              void* d_out, int out_size, void* d_ws, size_t ws_size,
                              hipStream_t stream) {
    const float* V     = (const float*)d_in[1];
    const float* R     = (const float*)d_in[2];
    const float* nw    = (const float*)d_in[3];
    const float* U     = (const float*)d_in[4];
    const float* w5    = (const float*)d_in[5];
    const float* b1    = (const float*)d_in[6];
    const float* noise = (const float*)d_in[7];
    const int*   C     = (const int*)d_in[8];
    float* out = (float*)d_out;

    float* colsum       = (float*)d_ws;
    unsigned short* Bp  = (unsigned short*)((char*)d_ws + 8192);
    unsigned int* maskT = (unsigned int*)((char*)d_ws + 8192 + 524288);

    hipMemsetAsync(colsum, 0, NTOP * sizeof(float), stream);
    hipMemsetAsync(out, 0, sizeof(float), stream);
    hipLaunchKernelGGL(k_prep, dim3(4, 125), dim3(256), 0, stream, nw, colsum);
    hipLaunchKernelGGL(k_vj, dim3(128), dim3(256), 0, stream,
                       V, noise, colsum, Bp);
    hipLaunchKernelGGL(k_cmask, dim3(MROWS / 32), dim3(256), 0, stream, C, maskT);
    hipLaunchKernelGGL(k_main, dim3(MROWS / 64), dim3(512), 0, stream,
                       U, w5, b1, (const short8*)Bp, R, maskT, out);
}

// Round 8
// 604.640 us; speedup vs baseline: 1.0233x; 1.0233x over previous
//
#include <hip/hip_runtime.h>
#include <hip/hip_bf16.h>

typedef __attribute__((ext_vector_type(8))) short short8;
typedef __attribute__((ext_vector_type(4))) float f32x4;

#define NTOP 1000
#define KC   256
#define MROWS 40000
#define ROWB 4000   // bytes per R/C row

static __device__ __forceinline__ unsigned short f2bf(float x) {
    union { float f; unsigned u; } v; v.f = x;
    unsigned r = (v.u + 0x7FFFu + ((v.u >> 16) & 1u)) >> 16;
    return (unsigned short)r;
}

static __device__ __forceinline__ void gl16(const void* src, void* dst) {
    __builtin_amdgcn_global_load_lds(
        (const __attribute__((address_space(1))) unsigned int*)src,
        (__attribute__((address_space(3))) unsigned int*)dst, 16, 0, 0);
}

// Kernel 1: colsum[j] += sum over an 8-row slab of nw. colsum pre-zeroed by memset.
__global__ void k_prep(const float* __restrict__ nw,
                       float* __restrict__ colsum) {
    int j  = blockIdx.x * 256 + threadIdx.x;
    int i0 = blockIdx.y * 8;
    if (j < NTOP) {
        float s = 0.f;
        int iend = min(i0 + 8, NTOP);
        for (int i = i0; i < iend; ++i) s += nw[(size_t)i * NTOP + j];
        atomicAdd(colsum + j, s);
    }
}

// Kernel 2: build B' in MFMA-fragment order:
//   B'[((nt*8 + s)*64 + lane)] (short8) = V_j[n = nt*16 + (lane&15),
//                                             k = s*32 + (lane>>4)*8 + j]
__global__ void k_vj(const float* __restrict__ V,
                     const float* __restrict__ noise,
                     const float* __restrict__ colsum,
                     unsigned short* __restrict__ Bp) {
    int t  = blockIdx.x * 256 + threadIdx.x;   // 0 .. 32767
    int nt = t >> 9;
    int s  = (t >> 6) & 7;
    int l  = t & 63;
    int lm = l & 15, lq = l >> 4;
    int n  = nt * 16 + lm;
    int k0 = s * 32 + lq * 8;
    union { short8 v; unsigned short us[8]; } pk;
    if (n < NTOP) {
        float cs = colsum[n];
        #pragma unroll
        for (int j = 0; j < 8; ++j) {
            int idx = n * KC + k0 + j;
            pk.us[j] = f2bf(V[idx] * cs + 0.1f * noise[idx]);
        }
    } else {
        #pragma unroll
        for (int j = 0; j < 8; ++j) pk.us[j] = 0;
    }
    reinterpret_cast<short8*>(Bp)[t] = pk.v;
}

// ---------------- k_main v9 ----------------
// M_BLK=64, 4 waves (wave owns rows wave*16..+16, all 32 cols per hs), grid 625.
// Counted-vmcnt pipeline, NEVER vmcnt(0) in the loop:
//  - Bf triple-buffered (3 x 16 KB): stage(hs+2) never touches the buffer
//    being read (hs%3) or the one in flight ((hs+1)%3).
//  - R and C double-buffered (2 x 8 KB each), WAVE-PRIVATE row slices (each
//    wave stages and reads only its own 16 rows -> no cross-wave race on the
//    (hs+2)&1 == hs&1 same-buffer restage; value-use + sched_barrier(0) orders
//    the restage after this iter's LDS reads).
//  - C streamed raw (int4): k_cmask ELIMINATED (-69 us on total).
//  - Per iter a wave issues exactly 8 VMEM (Bf 4, R 2, C 2); end-of-iter
//    s_waitcnt vmcnt(8) retires exactly the PREVIOUS iter's 8 stages before
//    the raw s_barrier. No register-VMEM in the loop.
// LDS: 48 + 16 + 16 = 80 KB -> 2 blocks/CU; grid 625 -> ~2.44 blocks/CU, one round.
__global__ __launch_bounds__(256, 2) void k_main(
    const float* __restrict__ U, const float* __restrict__ w5,
    const float* __restrict__ b1, const short8* __restrict__ Bf,
    const float* __restrict__ R, const int* __restrict__ C,
    float* __restrict__ out)
{
    __shared__ short8 BfL[3][1024];   // 3 x 16 KB
    __shared__ float4 RL[2][512];     // 2 x 8 KB  [buf][row*8 + slot]
    __shared__ int4   CL[2][512];     // 2 x 8 KB
    __shared__ float  red[4];

    const int tid  = threadIdx.x;
    const int wave = tid >> 6;
    const int l    = tid & 63;
    const int lm = l & 15;
    const int lq = l >> 4;
    const int rbase = blockIdx.x << 6;
    const int m  = rbase + (wave << 4) + lm;

    // ---- stage helpers (all linear lane*16 LDS dests, rule-21 compliant) ----
    auto stageBf = [&](int buf, int hs) {
        const char* src = (const char*)Bf + ((size_t)hs << 14) + (size_t)tid * 16;
        char*       dst = (char*)&BfL[buf][0] + (size_t)tid * 16;
        #pragma unroll
        for (int i = 0; i < 4; ++i) gl16(src + i * 4096, dst + i * 4096);
    };
    // R/C: slot S = (wave*2+p)*64 + l -> row = wave*16 + p*8 + (l>>3) (wave-private),
    // LDS slot s = l&7 holds logical chunk (s ^ (row&7)) -> reader XORs back.
    auto stageRC = [&](int buf, int hs) {
        #pragma unroll
        for (int p = 0; p < 2; ++p) {
            const int S   = ((wave * 2 + p) << 6) + l;
            const int row = S >> 3;
            const int c   = (S & 7) ^ (row & 7);
            int off = hs * 128 + c * 16;
            off = off < 3984 ? off : 3984;          // hs=31 tail clamp; masked later
            const size_t gb = (size_t)(rbase + row) * ROWB + off;
            gl16((const char*)R + gb, (char*)&RL[buf][0] + (size_t)S * 16);
            gl16((const char*)C + gb, (char*)&CL[buf][0] + (size_t)S * 16);
        }
    };

    // ---- prologue: stage hs=0,1 (16 VMEM); afr build hides the latency ----
    stageBf(0, 0); stageRC(0, 0);
    stageBf(1, 1); stageRC(1, 1);

    const float w0 = w5[0], w1 = w5[1], w2 = w5[2], w3 = w5[3], w4 = w5[4];
    const float bb = b1[0];
    short8 afr[8];
    #pragma unroll
    for (int s = 0; s < 8; ++s) {
        const float4* up4 = reinterpret_cast<const float4*>(
            U + (size_t)(m * KC + s * 32 + lq * 8) * 5);
        float u[40];
        #pragma unroll
        for (int i = 0; i < 10; ++i) {
            float4 t4 = up4[i];
            u[i*4+0] = t4.x; u[i*4+1] = t4.y; u[i*4+2] = t4.z; u[i*4+3] = t4.w;
        }
        union { short8 v; unsigned short us[8]; } pk;
        #pragma unroll
        for (int j = 0; j < 8; ++j) {
            const float* uu = u + j * 5;
            float e = uu[0]*w0 + uu[1]*w1 + uu[2]*w2 + uu[3]*w3 + uu[4]*w4 + bb;
            pk.us[j] = f2bf(e);
        }
        afr[s] = pk.v;
    }

    // U loads are retired (afr consumed them); outstanding = stage0(8) + stage1(8).
    // vmcnt(8) retires stage0; barrier makes buf0 visible to all waves.
    asm volatile("s_waitcnt vmcnt(8)" ::: "memory");
    __builtin_amdgcn_s_barrier();

    float lpsum = 0.f;
    int b0 = 0;   // Bf read buffer = hs%3

    for (int hs = 0; hs < 32; ++hs) {
        const int rc = hs & 1;

        // early stage of Bf(hs+2) into the untouched third buffer
        if (hs < 30) {
            const int tb = b0 == 0 ? 2 : (b0 == 1 ? 0 : 1);   // (b0+2)%3
            stageBf(tb, hs + 2);
        }

        // MFMA on buf b0 (16 ds_read_b128 + 16 MFMA, compiler interleaves)
        f32x4 acc0 = (f32x4){0.f,0.f,0.f,0.f};
        f32x4 acc1 = (f32x4){0.f,0.f,0.f,0.f};
        #pragma unroll
        for (int s = 0; s < 8; ++s) {
            const short8 bf0 = BfL[b0][(s << 6) + l];
            const short8 bf1 = BfL[b0][((8 + s) << 6) + l];
            acc0 = __builtin_amdgcn_mfma_f32_16x16x32_bf16(bf0, afr[s], acc0, 0, 0, 0);
            acc1 = __builtin_amdgcn_mfma_f32_16x16x32_bf16(bf1, afr[s], acc1, 0, 0, 0);
        }

        // R/C from LDS (swizzled slots; 2-way bank alias = free)
        const int rowl = (wave << 4) + lm;
        const int s0 = (rowl << 3) + (lq ^ (lm & 7));
        const int s1 = (rowl << 3) + ((4 + lq) ^ (lm & 7));
        const float4 r0 = RL[rc][s0], r1 = RL[rc][s1];
        const int4   c0 = CL[rc][s0], c1 = CL[rc][s1];

        // epilogue: lane holds m (fixed), n = hs*32 + tt*16 + lq*4 + r
        #pragma unroll
        for (int tt = 0; tt < 2; ++tt) {
            const float4& rv = tt ? r1 : r0;
            const int4&   cv = tt ? c1 : c0;
            const f32x4&  av = tt ? acc1 : acc0;
            const float* rp = reinterpret_cast<const float*>(&rv);
            const int*   cp = reinterpret_cast<const int*>(&cv);
            #pragma unroll
            for (int r = 0; r < 4; ++r) {
                const int n = hs * 32 + tt * 16 + lq * 4 + r;
                float x   = av[r];
                float muv = 1.f / (1.f + __expf(-x));
                float d   = rp[r] - muv;
                float lp  = -50.f * d * d + 1.3836465597893728f;
                if (cp[r] == 1 && n < NTOP) lpsum += lp;
            }
        }

        // restage R/C(hs+2) into the SAME buffer (rc) — after value-use; the
        // sched_barrier pins the gload issue below this iteration's LDS reads.
        __builtin_amdgcn_sched_barrier(0);
        if (hs < 30) stageRC(rc, hs + 2);

        // counted wait: retire last iter's 8 stages; keep this iter's 8 in flight.
        if (hs < 30) {
            asm volatile("s_waitcnt vmcnt(8)" ::: "memory");
        } else if (hs == 30) {
            asm volatile("s_waitcnt vmcnt(0)" ::: "memory");  // drain stage(31), ~1 iter old
        }
        if (hs < 31) __builtin_amdgcn_s_barrier();

        b0 = b0 == 2 ? 0 : b0 + 1;
    }

    #pragma unroll
    for (int off = 32; off > 0; off >>= 1) lpsum += __shfl_down(lpsum, off);
    if (l == 0) red[wave] = lpsum;
    __syncthreads();
    if (tid == 0) atomicAdd(out, red[0] + red[1] + red[2] + red[3]);
}

extern "C" void kernel_launch(void* const* d_in, const int* in_sizes, int n_in,
                              void* d_out, int out_size, void* d_ws, size_t ws_size,
                              hipStream_t stream) {
    const float* V     = (const float*)d_in[1];
    const float* R     = (const float*)d_in[2];
    const float* nw    = (const float*)d_in[3];
    const float* U     = (const float*)d_in[4];
    const float* w5    = (const float*)d_in[5];
    const float* b1    = (const float*)d_in[6];
    const float* noise = (const float*)d_in[7];
    const int*   C     = (const int*)d_in[8];
    float* out = (float*)d_out;

    float* colsum      = (float*)d_ws;
    unsigned short* Bp = (unsigned short*)((char*)d_ws + 8192);

    hipMemsetAsync(colsum, 0, NTOP * sizeof(float), stream);
    hipMemsetAsync(out, 0, sizeof(float), stream);
    hipLaunchKernelGGL(k_prep, dim3(4, 125), dim3(256), 0, stream, nw, colsum);
    hipLaunchKernelGGL(k_vj, dim3(128), dim3(256), 0, stream,
                       V, noise, colsum, Bp);
    hipLaunchKernelGGL(k_main, dim3(MROWS / 64), dim3(256), 0, stream,
                       U, w5, b1, (const short8*)Bp, R, C, out);
}

// Round 9
// 574.436 us; speedup vs baseline: 1.0771x; 1.0526x over previous
//
#include <hip/hip_runtime.h>
#include <hip/hip_bf16.h>

typedef __attribute__((ext_vector_type(8))) short short8;
typedef __attribute__((ext_vector_type(4))) float f32x4;

#define NTOP 1000
#define KC   256
#define MROWS 40000

static __device__ __forceinline__ unsigned short f2bf(float x) {
    union { float f; unsigned u; } v; v.f = x;
    unsigned r = (v.u + 0x7FFFu + ((v.u >> 16) & 1u)) >> 16;
    return (unsigned short)r;
}

static __device__ __forceinline__ void gl16(const void* src, void* dst) {
    __builtin_amdgcn_global_load_lds(
        (const __attribute__((address_space(1))) unsigned int*)src,
        (__attribute__((address_space(3))) unsigned int*)dst, 16, 0, 0);
}

// Kernel 1: colsum[j] += sum over an 8-row slab of nw. colsum pre-zeroed by memset.
__global__ void k_prep(const float* __restrict__ nw,
                       float* __restrict__ colsum) {
    int j  = blockIdx.x * 256 + threadIdx.x;
    int i0 = blockIdx.y * 8;
    if (j < NTOP) {
        float s = 0.f;
        int iend = min(i0 + 8, NTOP);
        for (int i = i0; i < iend; ++i) s += nw[(size_t)i * NTOP + j];
        atomicAdd(colsum + j, s);
    }
}

// Kernel 2: build B' (V_j) in MFMA-fragment order:
//   B'[((nt*8 + s)*64 + lane)] (short8) = V_j[n = nt*16 + (lane&15),
//                                             k = s*32 + (lane>>4)*8 + j]
__global__ void k_vj(const float* __restrict__ V,
                     const float* __restrict__ noise,
                     const float* __restrict__ colsum,
                     unsigned short* __restrict__ Bp) {
    int t  = blockIdx.x * 256 + threadIdx.x;   // 0 .. 32767
    int nt = t >> 9;
    int s  = (t >> 6) & 7;
    int l  = t & 63;
    int lm = l & 15, lq = l >> 4;
    int n  = nt * 16 + lm;
    int k0 = s * 32 + lq * 8;
    union { short8 v; unsigned short us[8]; } pk;
    if (n < NTOP) {
        float cs = colsum[n];
        #pragma unroll
        for (int j = 0; j < 8; ++j) {
            int idx = n * KC + k0 + j;
            pk.us[j] = f2bf(V[idx] * cs + 0.1f * noise[idx]);
        }
    } else {
        #pragma unroll
        for (int j = 0; j < 8; ++j) pk.us[j] = 0;
    }
    reinterpret_cast<short8*>(Bp)[t] = pk.v;
}

// Kernel 2c (NEW): U_emb precompute. Streams U (205 MB) fully coalesced and
// writes U_emb as bf16 in MFMA A-FRAGMENT order (20.5 MB):
//   Af[(mt*8+s)*64 + lane] = emb[m = mt*16+(lane&15)][k = s*32+(lane>>4)*8+j]
// Removes the scattered 80-load U prologue (and its u[40] VGPR hog) from k_main.
__global__ __launch_bounds__(256) void k_emb(const float* __restrict__ U,
                                             const float* __restrict__ w5,
                                             const float* __restrict__ b1,
                                             unsigned short* __restrict__ Af) {
    __shared__ float emb[16][257];   // +1 pad: phase-2 reads ~2-way (free)
    const int tid  = threadIdx.x;
    const int wave = tid >> 6;
    const int l    = tid & 63;
    const int mt   = blockIdx.x;

    const float w0 = w5[0], w1 = w5[1], w2 = w5[2], w3 = w5[3], w4 = w5[4];
    const float bb = b1[0];

    // Phase 1: 4 passes x 4 waves = 16 rows. Lane l owns k = 4l..4l+3:
    // 5 consecutive float4 (80 B/lane, dense) -> 4 dots in-register -> LDS.
    #pragma unroll
    for (int p = 0; p < 4; ++p) {
        const int r = p * 4 + wave;
        const float4* up = reinterpret_cast<const float4*>(
            U + (size_t)(mt * 16 + r) * (KC * 5) + l * 20);
        float f[20];
        #pragma unroll
        for (int i = 0; i < 5; ++i) {
            float4 t4 = up[i];
            f[i*4+0] = t4.x; f[i*4+1] = t4.y; f[i*4+2] = t4.z; f[i*4+3] = t4.w;
        }
        #pragma unroll
        for (int q = 0; q < 4; ++q) {
            const float* ff = f + q * 5;
            emb[r][l * 4 + q] = ff[0]*w0 + ff[1]*w1 + ff[2]*w2 + ff[3]*w3
                              + ff[4]*w4 + bb;
        }
    }
    __syncthreads();

    // Phase 2: thread -> fragments (s = wave, wave+4); coalesced 1 KB stores.
    const int lm = l & 15, lq = l >> 4;
    #pragma unroll
    for (int g = 0; g < 2; ++g) {
        const int s  = wave + g * 4;
        const int k0 = s * 32 + lq * 8;
        union { short8 v; unsigned short us[8]; } pk;
        #pragma unroll
        for (int j = 0; j < 8; ++j) pk.us[j] = f2bf(emb[lm][k0 + j]);
        reinterpret_cast<short8*>(Af)[(mt * 8 + s) * 64 + l] = pk.v;
    }
}

// ---------------- k_main v10 ----------------
// M_BLK=32, grid 1250, 4 waves = (wr m-half, wc n-half). No U prologue:
// A-fragments are 8 coalesced 1 KB loads from Af. LDS = Bf dbuf ONLY (32 KB)
// -> 4 blocks/CU (~50% occ). R/C: direct float4/int4, ONE ITER AHEAD.
// Counted vmcnt(2) before each raw barrier retires exactly the Bf stage and
// keeps R/C in flight — never vmcnt(0) in the loop.
__global__ __launch_bounds__(256, 4) void k_main(
    const short8* __restrict__ Af, const short8* __restrict__ Bf,
    const float* __restrict__ R, const int* __restrict__ C,
    float* __restrict__ out)
{
    __shared__ short8 BfL[2][1024];   // 2 x 16 KB

    const int tid  = threadIdx.x;
    const int wave = tid >> 6;
    const int l    = tid & 63;
    const int lm = l & 15;
    const int lq = l >> 4;
    const int wr = wave >> 1;          // m-half
    const int wc = wave & 1;           // n-half
    const int mt = blockIdx.x * 2 + wr;
    const int m  = mt * 16 + lm;

    auto stageBf = [&](int buf, int hs) {
        const char* src = (const char*)Bf + ((size_t)hs << 14) + (size_t)tid * 16;
        char*       dst = (char*)&BfL[buf][0] + (size_t)tid * 16;
        #pragma unroll
        for (int i = 0; i < 4; ++i) gl16(src + i * 4096, dst + i * 4096);
    };

    // prologue: stage(0) [4 VMEM], afr [8 VMEM], RC(0) [2 VMEM]
    stageBf(0, 0);
    short8 afr[8];
    #pragma unroll
    for (int s = 0; s < 8; ++s) afr[s] = Af[((mt * 8 + s) << 6) + l];

    const size_t rowbase = (size_t)m * NTOP;
    float4 r4c = *reinterpret_cast<const float4*>(R + rowbase + wc * 16 + lq * 4);
    int4   c4c = *reinterpret_cast<const int4*>(C + rowbase + wc * 16 + lq * 4);

    // retire stage(0) (oldest 4 of 14 outstanding); afr/RC keep flowing
    asm volatile("s_waitcnt vmcnt(10)" ::: "memory");
    __builtin_amdgcn_s_barrier();

    float lpsum = 0.f;

    for (int hs = 0; hs < 32; ++hs) {
        const int cur = hs & 1;

        if (hs < 31) stageBf(cur ^ 1, hs + 1);     // 4 VMEM (oldest this iter)
        __builtin_amdgcn_sched_barrier(0);          // pin: stage before RC

        float4 r4n = r4c; int4 c4n = c4c;
        if (hs < 31) {                              // 2 VMEM, consumed next iter
            int nb = (hs + 1) * 32 + wc * 16 + lq * 4;
            nb = nb < 996 ? nb : 996;               // tail clamp; masked below
            r4n = *reinterpret_cast<const float4*>(R + rowbase + nb);
            c4n = *reinterpret_cast<const int4*>(C + rowbase + nb);
        }

        f32x4 acc = (f32x4){0.f, 0.f, 0.f, 0.f};
        #pragma unroll
        for (int s = 0; s < 8; ++s) {
            const short8 bfr = BfL[cur][((wc * 8 + s) << 6) + l];
            acc = __builtin_amdgcn_mfma_f32_16x16x32_bf16(bfr, afr[s], acc, 0, 0, 0);
        }

        // epilogue(hs): lane holds m (fixed), n = hs*32 + wc*16 + lq*4 + r
        const float* rp = reinterpret_cast<const float*>(&r4c);
        const int*   cp = reinterpret_cast<const int*>(&c4c);
        #pragma unroll
        for (int r = 0; r < 4; ++r) {
            const int n = hs * 32 + wc * 16 + lq * 4 + r;
            float x   = acc[r];
            float muv = 1.f / (1.f + __expf(-x));
            float d   = rp[r] - muv;
            float lp  = -50.f * d * d + 1.3836465597893728f;
            if (cp[r] == 1 && n < NTOP) lpsum += lp;
        }

        if (hs < 31) {
            // retire stage(hs+1) (4 oldest), keep RC(hs+1) (2 newest) in flight
            asm volatile("s_waitcnt vmcnt(2)" ::: "memory");
            __builtin_amdgcn_s_barrier();
        }
        r4c = r4n; c4c = c4n;
    }

    #pragma unroll
    for (int off = 32; off > 0; off >>= 1) lpsum += __shfl_down(lpsum, off);
    if (l == 0) atomicAdd(out, lpsum);
}

// ---------------- fallback if workspace too small: inline U prologue ----------------
__global__ __launch_bounds__(256, 4) void k_main_fb(
    const float* __restrict__ U, const float* __restrict__ w5,
    const float* __restrict__ b1, const short8* __restrict__ Bf,
    const float* __restrict__ R, const int* __restrict__ C,
    float* __restrict__ out)
{
    __shared__ short8 BfL[2][1024];

    const int tid  = threadIdx.x;
    const int wave = tid >> 6;
    const int l    = tid & 63;
    const int lm = l & 15;
    const int lq = l >> 4;
    const int wr = wave >> 1;
    const int wc = wave & 1;
    const int mt = blockIdx.x * 2 + wr;
    const int m  = mt * 16 + lm;

    auto stageBf = [&](int buf, int hs) {
        const char* src = (const char*)Bf + ((size_t)hs << 14) + (size_t)tid * 16;
        char*       dst = (char*)&BfL[buf][0] + (size_t)tid * 16;
        #pragma unroll
        for (int i = 0; i < 4; ++i) gl16(src + i * 4096, dst + i * 4096);
    };

    stageBf(0, 0);
    const float w0 = w5[0], w1 = w5[1], w2 = w5[2], w3 = w5[3], w4 = w5[4];
    const float bb = b1[0];
    short8 afr[8];
    #pragma unroll
    for (int s = 0; s < 8; ++s) {
        const float4* up4 = reinterpret_cast<const float4*>(
            U + (size_t)(m * KC + s * 32 + lq * 8) * 5);
        float u[40];
        #pragma unroll
        for (int i = 0; i < 10; ++i) {
            float4 t4 = up4[i];
            u[i*4+0] = t4.x; u[i*4+1] = t4.y; u[i*4+2] = t4.z; u[i*4+3] = t4.w;
        }
        union { short8 v; unsigned short us[8]; } pk;
        #pragma unroll
        for (int j = 0; j < 8; ++j) {
            const float* uu = u + j * 5;
            pk.us[j] = f2bf(uu[0]*w0 + uu[1]*w1 + uu[2]*w2 + uu[3]*w3 + uu[4]*w4 + bb);
        }
        afr[s] = pk.v;
    }

    const size_t rowbase = (size_t)m * NTOP;
    float4 r4c = *reinterpret_cast<const float4*>(R + rowbase + wc * 16 + lq * 4);
    int4   c4c = *reinterpret_cast<const int4*>(C + rowbase + wc * 16 + lq * 4);

    asm volatile("s_waitcnt vmcnt(2)" ::: "memory");
    __builtin_amdgcn_s_barrier();

    float lpsum = 0.f;
    for (int hs = 0; hs < 32; ++hs) {
        const int cur = hs & 1;
        if (hs < 31) stageBf(cur ^ 1, hs + 1);
        __builtin_amdgcn_sched_barrier(0);
        float4 r4n = r4c; int4 c4n = c4c;
        if (hs < 31) {
            int nb = (hs + 1) * 32 + wc * 16 + lq * 4;
            nb = nb < 996 ? nb : 996;
            r4n = *reinterpret_cast<const float4*>(R + rowbase + nb);
            c4n = *reinterpret_cast<const int4*>(C + rowbase + nb);
        }
        f32x4 acc = (f32x4){0.f, 0.f, 0.f, 0.f};
        #pragma unroll
        for (int s = 0; s < 8; ++s) {
            const short8 bfr = BfL[cur][((wc * 8 + s) << 6) + l];
            acc = __builtin_amdgcn_mfma_f32_16x16x32_bf16(bfr, afr[s], acc, 0, 0, 0);
        }
        const float* rp = reinterpret_cast<const float*>(&r4c);
        const int*   cp = reinterpret_cast<const int*>(&c4c);
        #pragma unroll
        for (int r = 0; r < 4; ++r) {
            const int n = hs * 32 + wc * 16 + lq * 4 + r;
            float x   = acc[r];
            float muv = 1.f / (1.f + __expf(-x));
            float d   = rp[r] - muv;
            float lp  = -50.f * d * d + 1.3836465597893728f;
            if (cp[r] == 1 && n < NTOP) lpsum += lp;
        }
        if (hs < 31) {
            asm volatile("s_waitcnt vmcnt(2)" ::: "memory");
            __builtin_amdgcn_s_barrier();
        }
        r4c = r4n; c4c = c4n;
    }

    #pragma unroll
    for (int off = 32; off > 0; off >>= 1) lpsum += __shfl_down(lpsum, off);
    if (l == 0) atomicAdd(out, lpsum);
}

extern "C" void kernel_launch(void* const* d_in, const int* in_sizes, int n_in,
                              void* d_out, int out_size, void* d_ws, size_t ws_size,
                              hipStream_t stream) {
    const float* V     = (const float*)d_in[1];
    const float* R     = (const float*)d_in[2];
    const float* nw    = (const float*)d_in[3];
    const float* U     = (const float*)d_in[4];
    const float* w5    = (const float*)d_in[5];
    const float* b1    = (const float*)d_in[6];
    const float* noise = (const float*)d_in[7];
    const int*   C     = (const int*)d_in[8];
    float* out = (float*)d_out;

    float* colsum       = (float*)d_ws;
    unsigned short* Bp  = (unsigned short*)((char*)d_ws + 8192);
    unsigned short* Afp = (unsigned short*)((char*)d_ws + 8192 + 524288);
    const size_t ws_needed = 8192 + 524288 + (size_t)2500 * 8 * 64 * 16;

    hipMemsetAsync(colsum, 0, NTOP * sizeof(float), stream);
    hipMemsetAsync(out, 0, sizeof(float), stream);
    hipLaunchKernelGGL(k_prep, dim3(4, 125), dim3(256), 0, stream, nw, colsum);
    hipLaunchKernelGGL(k_vj, dim3(128), dim3(256), 0, stream,
                       V, noise, colsum, Bp);

    if (ws_size >= ws_needed) {
        hipLaunchKernelGGL(k_emb, dim3(2500), dim3(256), 0, stream,
                           U, w5, b1, Afp);
        hipLaunchKernelGGL(k_main, dim3(1250), dim3(256), 0, stream,
                           (const short8*)Afp, (const short8*)Bp, R, C, out);
    } else {
        hipLaunchKernelGGL(k_main_fb, dim3(1250), dim3(256), 0, stream,
                           U, w5, b1, (const short8*)Bp, R, C, out);
    }
}